// Round 10
// baseline (186.547 us; speedup 1.0000x reference)
//
#include <hip/hip_runtime.h>

// Problem constants (from reference: shape (32,1,512,512) fp32)
#define BATCH 32
#define H 512
#define W 512
#define N_TOT (BATCH * H * W)   // 8388608

// Round-10: persistent-wave version of round-4's proven body.
// Every round (1-9) showed OccupancyPercent pinned at 16-25% regardless of
// structure -- the scheduler holds only ~2 blocks/CU resident, so per-wave
// load-latency chains are exposed. Fix: launch exactly 256 blocks x 1024
// threads = 16 waves/CU, pinned resident for the whole kernel (one dispatch
// wave, no churn). Each block owns a 64-row band of one batch image and runs
// 2 iterations of the round-4 body (16 waves x 2 rows = 32 rows per iter).
// Body is unchanged from round 4: 30 independent float4 loads per wave per
// slab in 3 batches, shuffle halo, zero spill at 84-88 VGPR.

__device__ __forceinline__ void sobel_pass(const float* __restrict__ p,
                                           int base, int x0, int y0, int tx,
                                           float sob[2][8])
{
    float h1[4][8], h2[4][8];
#pragma unroll
    for (int rr = 0; rr < 4; ++rr) {
        const int yy = y0 - 1 + rr;
        const bool rv = (unsigned)yy < (unsigned)H;   // wave-uniform
        const float* row = p + base + yy * W + x0;
        float4 s1 = make_float4(0.f, 0.f, 0.f, 0.f), s2 = s1;
        if (rv) {
            s1 = *reinterpret_cast<const float4*>(row);       // cols x0..x0+3
            s2 = *reinterpret_cast<const float4*>(row + 4);   // cols x0+4..x0+7
        }
        float lw = __shfl_up(s2.w, 1, 64);    // lane tx-1's col x0-1
        if (tx == 0)  lw = 0.f;               // image left edge: zero-pad
        float rw = __shfl_down(s1.x, 1, 64);  // lane tx+1's col x0+8
        if (tx == 63) rw = 0.f;               // image right edge: zero-pad
        const float v[10] = {lw, s1.x, s1.y, s1.z, s1.w,
                             s2.x, s2.y, s2.z, s2.w, rw};
#pragma unroll
        for (int c = 0; c < 8; ++c) {
            h1[rr][c] = v[c + 2] - v[c];                    // row conv [-1,0,1]
            h2[rr][c] = v[c] + 2.f * v[c + 1] + v[c + 2];   // row conv [1,2,1]
        }
    }
#pragma unroll
    for (int o = 0; o < 2; ++o)
#pragma unroll
        for (int c = 0; c < 8; ++c) {
            const float gx = h1[o][c] + 2.f * h1[o + 1][c] + h1[o + 2][c];
            const float gy = h2[o][c] - h2[o + 2][c];
            sob[o][c] = fabsf(gx) + fabsf(gy);
        }
}

__global__ __launch_bounds__(1024)
void fusion_loss_kernel(const float* __restrict__ A,
                        const float* __restrict__ B,
                        const float* __restrict__ F,
                        const int* __restrict__ scheme_arr,
                        float* __restrict__ out)
{
    __shared__ float red[16];

    const int t   = threadIdx.x;
    const int tx  = t & 63;                  // lane: column group (8 px each)
    const int ty  = t >> 6;                  // wave 0..15: row pair
    const int x0  = tx << 3;
    const int b   = blockIdx.x >> 3;         // batch image (32)
    const int band = blockIdx.x & 7;         // 64-row band (8 per image)
    const int base = b * (H * W);
    const int scheme = scheme_arr[b];

    float acc = 0.f;

#pragma unroll 1   // sequential: one iteration's loads live at a time
    for (int it = 0; it < 2; ++it) {
        const int y0 = (band << 6) + (it << 5) + (ty << 1);

        // ---- l_loss mini-pass: rows y0,y0+1, own 8 cols (in-bounds) ----
#pragma unroll
        for (int rr = 0; rr < 2; ++rr) {
            const int ro = base + (y0 + rr) * W + x0;
            const float4 a0 = *reinterpret_cast<const float4*>(A + ro);
            const float4 a1 = *reinterpret_cast<const float4*>(A + ro + 4);
            const float4 b0 = *reinterpret_cast<const float4*>(B + ro);
            const float4 b1 = *reinterpret_cast<const float4*>(B + ro + 4);
            const float4 f0 = *reinterpret_cast<const float4*>(F + ro);
            const float4 f1 = *reinterpret_cast<const float4*>(F + ro + 4);
            const float av[8] = {a0.x, a0.y, a0.z, a0.w, a1.x, a1.y, a1.z, a1.w};
            const float bv[8] = {b0.x, b0.y, b0.z, b0.w, b1.x, b1.y, b1.z, b1.w};
            const float fv[8] = {f0.x, f0.y, f0.z, f0.w, f1.x, f1.y, f1.z, f1.w};
#pragma unroll
            for (int c = 0; c < 8; ++c) {
                const float ab = (scheme == 0) ? 0.5f * (av[c] + bv[c])
                               : (scheme == 1) ? fmaxf(av[c], bv[c])
                               : 0.f;
                acc += fabsf(ab - fv[c]);
            }
        }

        // ---- grad_loss: sequential per-image sobel, running max, fold F ----
        float sobM[2][8], sobT[2][8];
        sobel_pass(A, base, x0, y0, tx, sobM);
        sobel_pass(B, base, x0, y0, tx, sobT);
#pragma unroll
        for (int o = 0; o < 2; ++o)
#pragma unroll
            for (int c = 0; c < 8; ++c)
                sobM[o][c] = fmaxf(sobM[o][c], sobT[o][c]);
        sobel_pass(F, base, x0, y0, tx, sobT);
#pragma unroll
        for (int o = 0; o < 2; ++o)
#pragma unroll
            for (int c = 0; c < 8; ++c)
                acc += fabsf(sobT[o][c] - sobM[o][c]);
    }

    // ---- reduction: 64-lane shuffle, cross-wave via LDS, one atomic ----
#pragma unroll
    for (int off = 32; off > 0; off >>= 1)
        acc += __shfl_down(acc, off, 64);
    if (tx == 0) red[ty] = acc;
    __syncthreads();
    if (t < 64) {
        float s = (t < 16) ? red[t] : 0.f;
#pragma unroll
        for (int off = 8; off > 0; off >>= 1)
            s += __shfl_down(s, off, 64);
        if (t == 0)
            atomicAdd(out, s * (1.0f / (float)N_TOT));
    }
}

extern "C" void kernel_launch(void* const* d_in, const int* in_sizes, int n_in,
                              void* d_out, int out_size, void* d_ws, size_t ws_size,
                              hipStream_t stream)
{
    const float* A = (const float*)d_in[0];
    const float* B = (const float*)d_in[1];
    const float* F = (const float*)d_in[2];
    const int* scheme = (const int*)d_in[3];
    float* out = (float*)d_out;

    // d_out is poisoned before every launch; zero it for the atomics.
    hipMemsetAsync(out, 0, sizeof(float), stream);

    // 256 blocks x 1024 threads: 16 waves per CU, resident end-to-end.
    dim3 grid(BATCH * 8);   // 32 batches x 8 bands of 64 rows
    dim3 block(1024);
    fusion_loss_kernel<<<grid, block, 0, stream>>>(A, B, F, scheme, out);
}